// Round 7
// baseline (367.225 us; speedup 1.0000x reference)
//
#include <hip/hip_runtime.h>
#include <hip/hip_bf16.h>

typedef __attribute__((ext_vector_type(4))) float f32x4;
typedef __attribute__((ext_vector_type(8))) short short8;
typedef __attribute__((ext_vector_type(4))) unsigned short us4;
typedef unsigned short u16;

#define DEVI __device__ __forceinline__

#define BB 128      // batches
#define NN 256      // input patches per batch
#define MMEM 8      // memory tokens
#define DD 768      // embed dim
#define TT 264      // N + M
#define TP 320      // Vt col padding (zeros in cols 264..319)
#define AROWS2 33024  // 129*256: rows for the 256-tile GEMMs (x .. memory .. zero pad)

DEVI u16 f2bf(float f) {
  __hip_bfloat16 b = __float2bfloat16(f);
  u16 u; __builtin_memcpy(&u, &b, 2); return u;
}

DEVI void gload_lds16(const void* g, void* l) {
  __builtin_amdgcn_global_load_lds((const __attribute__((address_space(1))) void*)g,
                                   (__attribute__((address_space(3))) void*)l, 16, 0, 0);
}

// ---------------- conversion kernels ----------------

__global__ __launch_bounds__(256)
void conv_x(const float* __restrict__ x, const float* __restrict__ mem, u16* __restrict__ Ab) {
  const long total4 = (long)AROWS2 * DD / 4;
  for (long i = (long)blockIdx.x * blockDim.x + threadIdx.x; i < total4;
       i += (long)gridDim.x * blockDim.x) {
    long e = i * 4;
    int row = (int)(e / DD);
    int cb  = (int)(e % DD);
    f32x4 v = {0.f, 0.f, 0.f, 0.f};
    if (row < BB * NN)             v = *(const f32x4*)(x   + (size_t)row * DD + cb);
    else if (row < BB * NN + MMEM) v = *(const f32x4*)(mem + (size_t)(row - BB * NN) * DD + cb);
    us4 o = {f2bf(v[0]), f2bf(v[1]), f2bf(v[2]), f2bf(v[3])};
    *(us4*)(Ab + e) = o;
  }
}

__global__ __launch_bounds__(256)
void conv_w(const float* __restrict__ Wq, const float* __restrict__ Wk,
            const float* __restrict__ Wv, const float* __restrict__ Wo,
            u16* __restrict__ Wqt, u16* __restrict__ Wkt,
            u16* __restrict__ Wvt, u16* __restrict__ Wot) {
  const int total = 4 * DD * DD;
  for (int i = blockIdx.x * blockDim.x + threadIdx.x; i < total;
       i += gridDim.x * blockDim.x) {
    int mat = i / (DD * DD), rem = i % (DD * DD);
    int j = rem / DD, d = rem % DD;
    const float* W = (mat == 0) ? Wq : (mat == 1) ? Wk : (mat == 2) ? Wv : Wo;
    u16* Wt = (mat == 0) ? Wqt : (mat == 1) ? Wkt : (mat == 2) ? Wvt : Wot;
    Wt[(size_t)j * DD + d] = f2bf(W[(size_t)d * DD + j]);
  }
}

// ================= 256x256 8-wave B^T GEMM (K = 768) — round-4 structure =================
// (4 phases x 2 barriers, VM4 at phases 0/1/3, LGKM0+SCB after barrier;
//  measured 147 us / MfmaUtil 33% on G1.)

#define BAR()   __builtin_amdgcn_s_barrier()
#define SCB()   __builtin_amdgcn_sched_barrier(0)
#define LGKM0() asm volatile("s_waitcnt lgkmcnt(0)" ::: "memory")
#define VM4()   asm volatile("s_waitcnt vmcnt(4)" ::: "memory")
#define VMW0()  asm volatile("s_waitcnt vmcnt(0)" ::: "memory")
#define VMW3()  asm volatile("s_waitcnt vmcnt(3)" ::: "memory")

#define STG(gb, isB, ss, rg, kt) do {                                          \
    const u16* _s = (gb) + (size_t)((rg) * 16 + srow) * DD + (kt) * 64 + scol; \
    char* _d = smem + (ss) * 65536 + (isB) * 32768 + (rg) * 2048;              \
    gload_lds16(_s, _d);                                                       \
    gload_lds16(_s + 32, _d + 1024);                                           \
  } while (0)

#define STG_A0(ss, kt) STG(Ab, 0, ss, ((w & 3) | ((w & 4) << 1)), kt)
#define STG_B0(ss, kt) STG(Bb, 1, ss, ((w & 1) | ((w & 6) << 1)), kt)
#define STG_A1(ss, kt) STG(Ab, 0, ss, (((w & 3) | ((w & 4) << 1)) + 4), kt)
#define STG_B1(ss, kt) STG(Bb, 1, ss, (((w & 1) | ((w & 6) << 1)) + 2), kt)

#define RD_A(dst, s, QM)                                                          \
  _Pragma("unroll") for (int mi = 0; mi < 4; ++mi)                                \
  _Pragma("unroll") for (int ks = 0; ks < 2; ++ks)                                \
    dst[mi][ks] = *(const short8*)(smem + (s) * 65536 +                           \
                    ((wm * 8 + (QM) * 4 + mi) * 2 + ks) * 1024 + fbase);

#define RD_B(dst, s, QN)                                                          \
  _Pragma("unroll") for (int ni = 0; ni < 2; ++ni)                                \
  _Pragma("unroll") for (int ks = 0; ks < 2; ++ks)                                \
    dst[ni][ks] = *(const short8*)(smem + (s) * 65536 + 32768 +                   \
                    ((wn * 4 + (QN) * 2 + ni) * 2 + ks) * 1024 + fbase);

#define MM(FA, FB, QM, QN)                                                        \
  _Pragma("unroll") for (int mi = 0; mi < 4; ++mi)                                \
  _Pragma("unroll") for (int ni = 0; ni < 2; ++ni)                                \
  _Pragma("unroll") for (int ks = 0; ks < 2; ++ks)                                \
    acc[(QM)*4+mi][(QN)*2+ni] = __builtin_amdgcn_mfma_f32_16x16x32_bf16(          \
        FA[mi][ks], FB[ni][ks], acc[(QM)*4+mi][(QN)*2+ni], 0, 0, 0);

template<int MODE>
__global__ __launch_bounds__(512)
void gemm256(const u16* __restrict__ A, const u16* __restrict__ Bq,
             const u16* __restrict__ Bk, const u16* __restrict__ Bv,
             const float* __restrict__ b0, const float* __restrict__ b1,
             const float* __restrict__ b2,
             u16* __restrict__ Oq, u16* __restrict__ Ok, u16* __restrict__ Ov,
             float* __restrict__ FO, int NT)
{
  extern __shared__ char smem[];
  const int tid = threadIdx.x;
  const int l = tid & 63;
  const int w = tid >> 6;
  const int wm = w >> 2, wn = w & 3;

  // T1: bijective XCD swizzle (m204)
  const int nwg = gridDim.x * gridDim.y;
  const int lin = blockIdx.y * gridDim.x + blockIdx.x;
  const int qq = nwg >> 3, rr = nwg & 7;
  const int xcd = lin & 7, idx = lin >> 3;
  const int wg = (xcd < rr ? xcd * (qq + 1) : rr * (qq + 1) + (xcd - rr) * qq) + idx;
  const int tn = wg % gridDim.x, tm = wg / gridDim.x;

  const u16* Ab = A + (size_t)tm * 256 * DD;
  const u16* Bb;
  int matsel = 0;
  if constexpr (MODE == 0) {
    matsel = tn / 3;
    const u16* Wp = (matsel == 0) ? Bq : (matsel == 1) ? Bk : Bv;
    Bb = Wp + (size_t)(tn % 3) * 256 * DD;
  } else {
    Bb = Bq + (size_t)tn * 256 * DD;
  }

  const int jj = (l < 32) ? l : (l ^ 2);
  const int srow = jj >> 2;
  const int scol = (jj & 3) * 8;
  const int fbase = (((l & 15) * 64) + ((l >> 4) * 16)) ^ (((l >> 3) & 1) << 5);

  f32x4 acc[8][4];
  #pragma unroll
  for (int i = 0; i < 8; ++i)
    #pragma unroll
    for (int jx = 0; jx < 4; ++jx) acc[i][jx] = (f32x4){0.f, 0.f, 0.f, 0.f};

  short8 fa0[4][2], fa1[4][2], fb0[2][2], fb1[2][2];

  STG_A0(0, 0); STG_B0(0, 0); STG_A1(0, 0); STG_B1(0, 0);
  VM4(); BAR();

  for (int g = 0; g < NT; ++g) {
    const int s = g & 1, ss = s ^ 1;
    const int st = (g + 1 < NT) ? (g + 1) : 0;

    RD_A(fa0, s, 0); RD_B(fb0, s, 0);
    STG_A0(ss, st);
    BAR(); LGKM0(); SCB();
    __builtin_amdgcn_s_setprio(1); MM(fa0, fb0, 0, 0); __builtin_amdgcn_s_setprio(0);
    VM4(); BAR();

    RD_A(fa1, s, 1);
    STG_B0(ss, st);
    BAR(); LGKM0(); SCB();
    __builtin_amdgcn_s_setprio(1); MM(fa1, fb0, 1, 0); __builtin_amdgcn_s_setprio(0);
    VM4(); BAR();

    RD_B(fb1, s, 1);
    STG_A1(ss, st);
    BAR(); LGKM0(); SCB();
    __builtin_amdgcn_s_setprio(1); MM(fa1, fb1, 1, 1); __builtin_amdgcn_s_setprio(0);
    BAR();

    STG_B1(ss, st);
    BAR(); LGKM0(); SCB();
    __builtin_amdgcn_s_setprio(1); MM(fa0, fb1, 0, 1); __builtin_amdgcn_s_setprio(0);
    VM4(); BAR();
  }

  const int fr = l & 15, fro = (l >> 4) * 4;
  if constexpr (MODE == 0) {
    const float* bias = (matsel == 0) ? b0 : (matsel == 1) ? b1 : b2;
    u16* ob = (matsel == 0) ? Oq : (matsel == 1) ? Ok : Ov;
    const int cb = (tn % 3) * 256 + wn * 64;
    const size_t rb = (size_t)tm * 256 + wm * 128;
    #pragma unroll
    for (int MI = 0; MI < 8; ++MI)
      #pragma unroll
      for (int NI = 0; NI < 4; ++NI) {
        const int col = cb + NI * 16 + fr;
        const float bvv = bias[col];
        #pragma unroll
        for (int r = 0; r < 4; ++r)
          ob[(rb + MI * 16 + fro + r) * DD + col] = f2bf(acc[MI][NI][r] + bvv);
      }
  } else {
    const int cb = tn * 256 + wn * 64;
    const size_t rb = (size_t)tm * 256 + wm * 128;
    #pragma unroll
    for (int MI = 0; MI < 8; ++MI)
      #pragma unroll
      for (int NI = 0; NI < 4; ++NI) {
        const int col = cb + NI * 16 + fr;
        const float bvv = b0[col];
        #pragma unroll
        for (int r = 0; r < 4; ++r)
          FO[(rb + MI * 16 + fro + r) * DD + col] = acc[MI][NI][r] + bvv;
      }
  }
}

// ---------------- V transpose: Vt[b][d][t] (t padded to 320 with zeros) ----------------

__global__ __launch_bounds__(256)
void transpose_v(const u16* __restrict__ V, u16* __restrict__ Vt) {
  __shared__ u16 ls[64 * 66];
  const int b = blockIdx.z;
  const int d0 = blockIdx.x * 64;
  const int t0 = blockIdx.y * 64;
  const int tid = threadIdx.x;
  #pragma unroll
  for (int q = 0; q < 2; ++q) {
    const int idx = q * 256 + tid;
    const int tr = idx >> 3;
    const int dg = (idx & 7) * 8;
    const int t = t0 + tr;
    short8 v = (short8)(short)0;
    if (t < NN)       v = *(const short8*)(V + ((size_t)b * NN + t) * DD + d0 + dg);
    else if (t < TT)  v = *(const short8*)(V + (size_t)(BB * NN + t - NN) * DD + d0 + dg);
    #pragma unroll
    for (int e = 0; e < 8; ++e) ls[tr * 66 + dg + e] = (u16)v[e];
  }
  __syncthreads();
  #pragma unroll
  for (int q = 0; q < 2; ++q) {
    const int idx = q * 256 + tid;
    const int dr = idx >> 3;
    const int tg = (idx & 7) * 8;
    short8 v;
    #pragma unroll
    for (int e = 0; e < 8; ++e) v[e] = (short)ls[(tg + e) * 66 + dr];
    *(short8*)(Vt + ((size_t)b * DD + d0 + dr) * TP + t0 + tg) = v;
  }
}

// ================= fused attention: S = QK^T*scale -> softmax -> O = P V =================
// One block per (q-tile of 128, batch): 256 blocks, 8 waves, LDS 124 KiB -> 1 block/CU.
// ROUND-7 FIX: phase-B V staging was missing the per-batch offset (read batch 0's V
// for every block). Vtb = Vt + b*DD*TP now applied at both staging sites.

#define PPITCH 592   // P row pitch bytes (296 u16)
#define POFF   51200 // P region LDS offset
#define VSLOT  24576 // phase-B V slot size

__global__ __launch_bounds__(512)
void fused_attn(const u16* __restrict__ Qb, const u16* __restrict__ Kb,
                const u16* __restrict__ Vt, u16* __restrict__ O)
{
  extern __shared__ char smem[];
  const int tid = threadIdx.x;
  const int l = tid & 63;
  const int w = tid >> 6;
  const int qt = blockIdx.x;
  const int b  = blockIdx.y;

  const int jj = (l < 32) ? l : (l ^ 2);
  const int srow = jj >> 2;
  const int scol = (jj & 3) * 8;
  const int fbase = (((l & 15) * 64) + ((l >> 4) * 16)) ^ (((l >> 3) & 1) << 5);
  const int fr = l & 15, g4 = l >> 4;

  // ---- phase A ----
  f32x4 accS[17];
  #pragma unroll
  for (int i = 0; i < 17; ++i) accS[i] = (f32x4){0.f, 0.f, 0.f, 0.f};

  const u16* Qrow0 = Qb + ((size_t)b * NN + qt * 128) * DD;

  for (int kt = 0; kt < 12; ++kt) {
    const int kpos = kt * 64 + scol;
    { // Q rgroup w
      const u16* src = Qrow0 + (size_t)(w * 16 + srow) * DD + kpos;
      char* dst = smem + w * 2048;
      gload_lds16(src, dst); gload_lds16(src + 32, dst + 1024);
    }
    #pragma unroll
    for (int rep = 0; rep < 2; ++rep) { // K rgroups w, w+8
      const int rg = w + rep * 8;
      const int kr = rg * 16 + srow;
      const int grow = (kr < NN) ? (b * NN + kr) : (BB * NN + kr - NN);
      const u16* src = Kb + (size_t)grow * DD + kpos;
      char* dst = smem + 16384 + rg * 2048;
      gload_lds16(src, dst); gload_lds16(src + 32, dst + 1024);
    }
    if (w == 0) { // K rgroup 16 (memory rows + pad, pad masked later)
      const int grow = BB * NN + srow;
      const u16* src = Kb + (size_t)grow * DD + kpos;
      char* dst = smem + 16384 + 16 * 2048;
      gload_lds16(src, dst); gload_lds16(src + 32, dst + 1024);
    }
    VMW0(); BAR();

    short8 aq0 = *(const short8*)(smem + (w * 2 + 0) * 1024 + fbase);
    short8 aq1 = *(const short8*)(smem + (w * 2 + 1) * 1024 + fbase);
    #pragma unroll
    for (int ni = 0; ni < 17; ++ni) {
      short8 bk0 = *(const short8*)(smem + 16384 + (ni * 2 + 0) * 1024 + fbase);
      short8 bk1 = *(const short8*)(smem + 16384 + (ni * 2 + 1) * 1024 + fbase);
      accS[ni] = __builtin_amdgcn_mfma_f32_16x16x32_bf16(aq0, bk0, accS[ni], 0, 0, 0);
      accS[ni] = __builtin_amdgcn_mfma_f32_16x16x32_bf16(aq1, bk1, accS[ni], 0, 0, 0);
    }
    BAR();
  }

  // ---- softmax (in-register) ----
  const float scl = 0.03608439182435161f;  // 768^-0.5
  #pragma unroll
  for (int ni = 0; ni < 17; ++ni) {
    #pragma unroll
    for (int r = 0; r < 4; ++r) accS[ni][r] *= scl;
  }
  if (fr >= 8) { // mask pad keys t = 264..271
    #pragma unroll
    for (int r = 0; r < 4; ++r) accS[16][r] = -1e30f;
  }
  #pragma unroll
  for (int r = 0; r < 4; ++r) {
    float mv = -1e30f;
    #pragma unroll
    for (int ni = 0; ni < 17; ++ni) mv = fmaxf(mv, accS[ni][r]);
    #pragma unroll
    for (int off = 8; off; off >>= 1) mv = fmaxf(mv, __shfl_xor(mv, off));
    float sum = 0.f;
    #pragma unroll
    for (int ni = 0; ni < 17; ++ni) {
      float e = __expf(accS[ni][r] - mv);
      accS[ni][r] = e;
      sum += e;
    }
    #pragma unroll
    for (int off = 8; off; off >>= 1) sum += __shfl_xor(sum, off);
    const float inv = 1.f / sum;
    const int q = w * 16 + g4 * 4 + r;
    char* prow = smem + POFF + q * PPITCH;
    #pragma unroll
    for (int ni = 0; ni < 17; ++ni)
      *(u16*)(prow + (ni * 16 + fr) * 2) = f2bf(accS[ni][r] * inv);
    *(u16*)(prow + (272 + fr) * 2) = 0;  // zero t 272..287
  }
  __syncthreads();

  // ---- phase B: O = P @ V^T ----
  const u16* Vtb = Vt + (size_t)b * DD * TP;   // FIX: per-batch V^T base
  const int qh = w >> 2, dq = w & 3;
  f32x4 accO[4][6];

  // prologue: stage (pass 0, chunk 0) into slot 0
  {
    #pragma unroll
    for (int rep = 0; rep < 3; ++rep) {
      const int rg = w * 3 + rep;
      const u16* src = Vtb + (size_t)(rg * 16 + srow) * TP + scol;
      gload_lds16(src, smem + rg * 1024);
    }
  }

  int cur = 0;
  for (int p = 0; p < 2; ++p) {
    #pragma unroll
    for (int mi = 0; mi < 4; ++mi)
      #pragma unroll
      for (int nj = 0; nj < 6; ++nj) accO[mi][nj] = (f32x4){0.f, 0.f, 0.f, 0.f};

    for (int tc = 0; tc < 9; ++tc) {
      int np = p, nc = tc + 1;
      if (nc == 9) { np = p + 1; nc = 0; }
      if (np == 2) { np = 1; nc = 8; }   // dead stage on final iteration
      BAR();                              // prior compute consumed slot cur^1
      {
        #pragma unroll
        for (int rep = 0; rep < 3; ++rep) {
          const int rg = w * 3 + rep;
          const u16* src = Vtb + (size_t)(np * 384 + rg * 16 + srow) * TP + nc * 32 + scol;
          gload_lds16(src, smem + (cur ^ 1) * VSLOT + rg * 1024);
        }
      }
      VMW3();                             // slot cur's 3 loads complete
      BAR();

      short8 pa[4], vb[6];
      #pragma unroll
      for (int mi = 0; mi < 4; ++mi)
        pa[mi] = *(const short8*)(smem + POFF +
                   (qh * 64 + mi * 16 + fr) * PPITCH + tc * 64 + g4 * 16);
      #pragma unroll
      for (int nj = 0; nj < 6; ++nj)
        vb[nj] = *(const short8*)(smem + cur * VSLOT + (dq * 6 + nj) * 1024 + fbase);
      __builtin_amdgcn_s_setprio(1);
      #pragma unroll
      for (int mi = 0; mi < 4; ++mi)
        #pragma unroll
        for (int nj = 0; nj < 6; ++nj)
          accO[mi][nj] = __builtin_amdgcn_mfma_f32_16x16x32_bf16(pa[mi], vb[nj], accO[mi][nj], 0, 0, 0);
      __builtin_amdgcn_s_setprio(0);
      cur ^= 1;
    }

    u16* Ob = O + ((size_t)b * NN + qt * 128 + qh * 64) * DD + p * 384 + dq * 96;
    #pragma unroll
    for (int mi = 0; mi < 4; ++mi)
      #pragma unroll
      for (int nj = 0; nj < 6; ++nj)
        #pragma unroll
        for (int r = 0; r < 4; ++r)
          Ob[(size_t)(mi * 16 + g4 * 4 + r) * DD + nj * 16 + fr] = f2bf(accO[mi][nj][r]);
  }
}

// ---------------- launch ----------------
// Order: conv_x, conv_w -> G1 -> transpose_v -> fused_attn -> G3.
// d_out (100.66 MB): Ab [0,50.72M) live conv_x->G1; W^T(q,k,v) [97.12M,100.66M)
//   live conv_w->G1; Vt [0,62.91M) live transpose_v->fused (over dead Ab);
//   all dead before G3 writes d_out.
// ws (high-water 153.35 MB, proven safe): Qb@0, Kb@50.72M (live G1->fused);
//   Vb@101.45M (live G1->transpose_v); O@101.45M over dead Vb (live fused->G3);
//   Wot@152.17M (live conv_w->G3).

extern "C" void kernel_launch(void* const* d_in, const int* in_sizes, int n_in,
                              void* d_out, int out_size, void* d_ws, size_t ws_size,
                              hipStream_t stream) {
  const float* x   = (const float*)d_in[0];
  const float* mem = (const float*)d_in[1];
  const float* Wq  = (const float*)d_in[2];
  const float* bq  = (const float*)d_in[3];
  const float* Wk  = (const float*)d_in[4];
  const float* bk  = (const float*)d_in[5];
  const float* Wv  = (const float*)d_in[6];
  const float* bv  = (const float*)d_in[7];
  const float* Wo  = (const float*)d_in[8];
  const float* bo  = (const float*)d_in[9];
  float* out = (float*)d_out;
  (void)ws_size; (void)in_sizes; (void)n_in; (void)out_size;

  const size_t QKV_B = (size_t)AROWS2 * DD * 2;        // 50,724,864
  char* wsb = (char*)d_ws;
  u16* Qb  = (u16*)(wsb);
  u16* Kb  = (u16*)(wsb + QKV_B);
  u16* Vb  = (u16*)(wsb + 2 * QKV_B);
  u16* O   = (u16*)(wsb + 2 * QKV_B);                  // over Vb (dead after transpose_v)
  u16* Wot = (u16*)(wsb + 3 * QKV_B);

  u16*   Ab  = (u16*)d_out;                            // live conv_x -> G1
  u16*   Vt  = (u16*)d_out;                            // live transpose_v -> fused (over dead Ab)
  u16*   Wqt = (u16*)((char*)d_out + 97124352);        // live conv_w -> G1
  u16*   Wkt = Wqt + (size_t)DD * DD;
  u16*   Wvt = Wkt + (size_t)DD * DD;

  conv_x<<<2048, 256, 0, stream>>>(x, mem, Ab);
  conv_w<<<1024, 256, 0, stream>>>(Wq, Wk, Wv, Wo, Wqt, Wkt, Wvt, Wot);

  // G1: QKV projection  [33024 x 2304] = Ab @ [Wqt|Wkt|Wvt]^T  (+bias, -> bf16)
  gemm256<0><<<dim3(9, 129), 512, 131072, stream>>>(
      Ab, Wqt, Wkt, Wvt, bq, bk, bv, Qb, Kb, Vb, nullptr, DD / 64);

  // Vt[b][d][t] (writes d_out over dead Ab)
  transpose_v<<<dim3(12, 5, BB), 256, 0, stream>>>(Vb, Vt);

  // fused attention: Qb, Kb, Vt -> O (bf16 [32768][768], over dead Vb)
  fused_attn<<<dim3(2, BB), 512, 126976, stream>>>(Qb, Kb, Vt, O);

  // G3: out = O @ Wot^T + bo  (fp32)
  gemm256<1><<<dim3(3, 128), 512, 131072, stream>>>(
      O, Wot, nullptr, nullptr, bo, nullptr, nullptr,
      nullptr, nullptr, nullptr, out, DD / 64);
}

// Round 8
// 356.226 us; speedup vs baseline: 1.0309x; 1.0309x over previous
//
#include <hip/hip_runtime.h>
#include <hip/hip_bf16.h>

typedef __attribute__((ext_vector_type(4))) float f32x4;
typedef __attribute__((ext_vector_type(8))) short short8;
typedef __attribute__((ext_vector_type(4))) unsigned short us4;
typedef unsigned short u16;

#define DEVI __device__ __forceinline__

#define BB 128      // batches
#define NN 256      // input patches per batch
#define MMEM 8      // memory tokens
#define DD 768      // embed dim
#define TT 264      // N + M
#define TP 320      // Vt col padding (zeros in cols 264..319)
#define AROWS2 33024  // 129*256: rows for the 256-tile GEMMs (x .. memory .. zero pad)

DEVI u16 f2bf(float f) {
  __hip_bfloat16 b = __float2bfloat16(f);
  u16 u; __builtin_memcpy(&u, &b, 2); return u;
}

DEVI void gload_lds16(const void* g, void* l) {
  __builtin_amdgcn_global_load_lds((const __attribute__((address_space(1))) void*)g,
                                   (__attribute__((address_space(3))) void*)l, 16, 0, 0);
}

// ---------------- conversion kernels ----------------

__global__ __launch_bounds__(256)
void conv_x(const float* __restrict__ x, const float* __restrict__ mem, u16* __restrict__ Ab) {
  const long total4 = (long)AROWS2 * DD / 4;
  for (long i = (long)blockIdx.x * blockDim.x + threadIdx.x; i < total4;
       i += (long)gridDim.x * blockDim.x) {
    long e = i * 4;
    int row = (int)(e / DD);
    int cb  = (int)(e % DD);
    f32x4 v = {0.f, 0.f, 0.f, 0.f};
    if (row < BB * NN)             v = *(const f32x4*)(x   + (size_t)row * DD + cb);
    else if (row < BB * NN + MMEM) v = *(const f32x4*)(mem + (size_t)(row - BB * NN) * DD + cb);
    us4 o = {f2bf(v[0]), f2bf(v[1]), f2bf(v[2]), f2bf(v[3])};
    *(us4*)(Ab + e) = o;
  }
}

__global__ __launch_bounds__(256)
void conv_w(const float* __restrict__ Wq, const float* __restrict__ Wk,
            const float* __restrict__ Wv, const float* __restrict__ Wo,
            u16* __restrict__ Wqt, u16* __restrict__ Wkt,
            u16* __restrict__ Wvt, u16* __restrict__ Wot) {
  const int total = 4 * DD * DD;
  for (int i = blockIdx.x * blockDim.x + threadIdx.x; i < total;
       i += gridDim.x * blockDim.x) {
    int mat = i / (DD * DD), rem = i % (DD * DD);
    int j = rem / DD, d = rem % DD;
    const float* W = (mat == 0) ? Wq : (mat == 1) ? Wk : (mat == 2) ? Wv : Wo;
    u16* Wt = (mat == 0) ? Wqt : (mat == 1) ? Wkt : (mat == 2) ? Wvt : Wot;
    Wt[(size_t)j * DD + d] = f2bf(W[(size_t)d * DD + j]);
  }
}

// ================= 256x256 8-wave B^T GEMM (K = 768) — round-4 structure =================
// (unchanged: 4 phases x 2 barriers, VM4 at phases 0/1/3; 147 us / 33% MfmaUtil on G1)

#define BAR()   __builtin_amdgcn_s_barrier()
#define SCB()   __builtin_amdgcn_sched_barrier(0)
#define LGKM0() asm volatile("s_waitcnt lgkmcnt(0)" ::: "memory")
#define VM4()   asm volatile("s_waitcnt vmcnt(4)" ::: "memory")
#define VMW0()  asm volatile("s_waitcnt vmcnt(0)" ::: "memory")
#define VMW3()  asm volatile("s_waitcnt vmcnt(3)" ::: "memory")

#define STG(gb, isB, ss, rg, kt) do {                                          \
    const u16* _s = (gb) + (size_t)((rg) * 16 + srow) * DD + (kt) * 64 + scol; \
    char* _d = smem + (ss) * 65536 + (isB) * 32768 + (rg) * 2048;              \
    gload_lds16(_s, _d);                                                       \
    gload_lds16(_s + 32, _d + 1024);                                           \
  } while (0)

#define STG_A0(ss, kt) STG(Ab, 0, ss, ((w & 3) | ((w & 4) << 1)), kt)
#define STG_B0(ss, kt) STG(Bb, 1, ss, ((w & 1) | ((w & 6) << 1)), kt)
#define STG_A1(ss, kt) STG(Ab, 0, ss, (((w & 3) | ((w & 4) << 1)) + 4), kt)
#define STG_B1(ss, kt) STG(Bb, 1, ss, (((w & 1) | ((w & 6) << 1)) + 2), kt)

#define RD_A(dst, s, QM)                                                          \
  _Pragma("unroll") for (int mi = 0; mi < 4; ++mi)                                \
  _Pragma("unroll") for (int ks = 0; ks < 2; ++ks)                                \
    dst[mi][ks] = *(const short8*)(smem + (s) * 65536 +                           \
                    ((wm * 8 + (QM) * 4 + mi) * 2 + ks) * 1024 + fbase);

#define RD_B(dst, s, QN)                                                          \
  _Pragma("unroll") for (int ni = 0; ni < 2; ++ni)                                \
  _Pragma("unroll") for (int ks = 0; ks < 2; ++ks)                                \
    dst[ni][ks] = *(const short8*)(smem + (s) * 65536 + 32768 +                   \
                    ((wn * 4 + (QN) * 2 + ni) * 2 + ks) * 1024 + fbase);

#define MM(FA, FB, QM, QN)                                                        \
  _Pragma("unroll") for (int mi = 0; mi < 4; ++mi)                                \
  _Pragma("unroll") for (int ni = 0; ni < 2; ++ni)                                \
  _Pragma("unroll") for (int ks = 0; ks < 2; ++ks)                                \
    acc[(QM)*4+mi][(QN)*2+ni] = __builtin_amdgcn_mfma_f32_16x16x32_bf16(          \
        FA[mi][ks], FB[ni][ks], acc[(QM)*4+mi][(QN)*2+ni], 0, 0, 0);

template<int MODE>
__global__ __launch_bounds__(512)
void gemm256(const u16* __restrict__ A, const u16* __restrict__ Bq,
             const u16* __restrict__ Bk, const u16* __restrict__ Bv,
             const float* __restrict__ b0, const float* __restrict__ b1,
             const float* __restrict__ b2,
             u16* __restrict__ Oq, u16* __restrict__ Ok, u16* __restrict__ Ov,
             float* __restrict__ FO, int NT)
{
  extern __shared__ char smem[];
  const int tid = threadIdx.x;
  const int l = tid & 63;
  const int w = tid >> 6;
  const int wm = w >> 2, wn = w & 3;

  // T1: bijective XCD swizzle (m204)
  const int nwg = gridDim.x * gridDim.y;
  const int lin = blockIdx.y * gridDim.x + blockIdx.x;
  const int qq = nwg >> 3, rr = nwg & 7;
  const int xcd = lin & 7, idx = lin >> 3;
  const int wg = (xcd < rr ? xcd * (qq + 1) : rr * (qq + 1) + (xcd - rr) * qq) + idx;
  const int tn = wg % gridDim.x, tm = wg / gridDim.x;

  const u16* Ab = A + (size_t)tm * 256 * DD;
  const u16* Bb;
  int matsel = 0;
  if constexpr (MODE == 0) {
    matsel = tn / 3;
    const u16* Wp = (matsel == 0) ? Bq : (matsel == 1) ? Bk : Bv;
    Bb = Wp + (size_t)(tn % 3) * 256 * DD;
  } else {
    Bb = Bq + (size_t)tn * 256 * DD;
  }

  const int jj = (l < 32) ? l : (l ^ 2);
  const int srow = jj >> 2;
  const int scol = (jj & 3) * 8;
  const int fbase = (((l & 15) * 64) + ((l >> 4) * 16)) ^ (((l >> 3) & 1) << 5);

  f32x4 acc[8][4];
  #pragma unroll
  for (int i = 0; i < 8; ++i)
    #pragma unroll
    for (int jx = 0; jx < 4; ++jx) acc[i][jx] = (f32x4){0.f, 0.f, 0.f, 0.f};

  short8 fa0[4][2], fa1[4][2], fb0[2][2], fb1[2][2];

  STG_A0(0, 0); STG_B0(0, 0); STG_A1(0, 0); STG_B1(0, 0);
  VM4(); BAR();

  for (int g = 0; g < NT; ++g) {
    const int s = g & 1, ss = s ^ 1;
    const int st = (g + 1 < NT) ? (g + 1) : 0;

    RD_A(fa0, s, 0); RD_B(fb0, s, 0);
    STG_A0(ss, st);
    BAR(); LGKM0(); SCB();
    __builtin_amdgcn_s_setprio(1); MM(fa0, fb0, 0, 0); __builtin_amdgcn_s_setprio(0);
    VM4(); BAR();

    RD_A(fa1, s, 1);
    STG_B0(ss, st);
    BAR(); LGKM0(); SCB();
    __builtin_amdgcn_s_setprio(1); MM(fa1, fb0, 1, 0); __builtin_amdgcn_s_setprio(0);
    VM4(); BAR();

    RD_B(fb1, s, 1);
    STG_A1(ss, st);
    BAR(); LGKM0(); SCB();
    __builtin_amdgcn_s_setprio(1); MM(fa1, fb1, 1, 1); __builtin_amdgcn_s_setprio(0);
    BAR();

    STG_B1(ss, st);
    BAR(); LGKM0(); SCB();
    __builtin_amdgcn_s_setprio(1); MM(fa0, fb1, 0, 1); __builtin_amdgcn_s_setprio(0);
    VM4(); BAR();
  }

  const int fr = l & 15, fro = (l >> 4) * 4;
  if constexpr (MODE == 0) {
    const float* bias = (matsel == 0) ? b0 : (matsel == 1) ? b1 : b2;
    u16* ob = (matsel == 0) ? Oq : (matsel == 1) ? Ok : Ov;
    const int cb = (tn % 3) * 256 + wn * 64;
    const size_t rb = (size_t)tm * 256 + wm * 128;
    #pragma unroll
    for (int MI = 0; MI < 8; ++MI)
      #pragma unroll
      for (int NI = 0; NI < 4; ++NI) {
        const int col = cb + NI * 16 + fr;
        const float bvv = bias[col];
        #pragma unroll
        for (int r = 0; r < 4; ++r)
          ob[(rb + MI * 16 + fro + r) * DD + col] = f2bf(acc[MI][NI][r] + bvv);
      }
  } else {
    const int cb = tn * 256 + wn * 64;
    const size_t rb = (size_t)tm * 256 + wm * 128;
    #pragma unroll
    for (int MI = 0; MI < 8; ++MI)
      #pragma unroll
      for (int NI = 0; NI < 4; ++NI) {
        const int col = cb + NI * 16 + fr;
        const float bvv = b0[col];
        #pragma unroll
        for (int r = 0; r < 4; ++r)
          FO[(rb + MI * 16 + fro + r) * DD + col] = acc[MI][NI][r] + bvv;
      }
  }
}

// ---------------- V transpose: Vt[b][d][t] (t padded to 320 with zeros) ----------------

__global__ __launch_bounds__(256)
void transpose_v(const u16* __restrict__ V, u16* __restrict__ Vt) {
  __shared__ u16 ls[64 * 66];
  const int b = blockIdx.z;
  const int d0 = blockIdx.x * 64;
  const int t0 = blockIdx.y * 64;
  const int tid = threadIdx.x;
  #pragma unroll
  for (int q = 0; q < 2; ++q) {
    const int idx = q * 256 + tid;
    const int tr = idx >> 3;
    const int dg = (idx & 7) * 8;
    const int t = t0 + tr;
    short8 v = (short8)(short)0;
    if (t < NN)       v = *(const short8*)(V + ((size_t)b * NN + t) * DD + d0 + dg);
    else if (t < TT)  v = *(const short8*)(V + (size_t)(BB * NN + t - NN) * DD + d0 + dg);
    #pragma unroll
    for (int e = 0; e < 8; ++e) ls[tr * 66 + dg + e] = (u16)v[e];
  }
  __syncthreads();
  #pragma unroll
  for (int q = 0; q < 2; ++q) {
    const int idx = q * 256 + tid;
    const int dr = idx >> 3;
    const int tg = (idx & 7) * 8;
    short8 v;
    #pragma unroll
    for (int e = 0; e < 8; ++e) v[e] = (short)ls[(tg + e) * 66 + dr];
    *(short8*)(Vt + ((size_t)b * DD + d0 + dr) * TP + t0 + tg) = v;
  }
}

// ================= fused attention: S = QK^T*scale -> softmax -> O = P V =================
// ROUND-8 restructure (phase A was vmcnt(0)-drain-per-step = exposed HBM latency x12):
//  - phase A double-buffered: stage kt+1 -> slot ss, counted vmcnt(6|8), 2 bars/step;
//    drain happens under ~2300 cyc of compute.
//  - XCD pairing: both q-tile blocks of a batch mapped to the same XCD -> K/V L2 hits.
//  - LDS overlay: 2x51200 phase-A slots; P[75776 B]@0 and V slots@75776 reuse the
//    region AFTER a full vmcnt(0) drain + barrier (dead stages would clobber P).
// LDS layout: phaseA slot0 @0, slot1 @51200 (each: Q 16K + K 17x2K).
//             P @0 (128 rows x 592 B). V dbuf @75776, 2 x 24576. Total 124928.

#define ASLOT  51200
#define PPITCH 592
#define VOFF   75776
#define VSLOT  24576

#define STAGE_A(kt, slot) do {                                                   \
    const int kpos_ = (kt) * 64 + scol;                                          \
    char* sb_ = smem + (slot) * ASLOT;                                           \
    const u16* qs_ = Qrow0 + (size_t)(w * 16 + srow) * DD + kpos_;               \
    gload_lds16(qs_, sb_ + w * 2048);                                            \
    gload_lds16(qs_ + 32, sb_ + w * 2048 + 1024);                                \
    _Pragma("unroll") for (int rep_ = 0; rep_ < 2; ++rep_) {                     \
      const int rg_ = w + rep_ * 8;                                              \
      const int kr_ = rg_ * 16 + srow;                                           \
      const int grow_ = (kr_ < NN) ? (b * NN + kr_) : (BB * NN + kr_ - NN);      \
      const u16* ks_ = Kb + (size_t)grow_ * DD + kpos_;                          \
      char* kd_ = sb_ + 16384 + rg_ * 2048;                                      \
      gload_lds16(ks_, kd_); gload_lds16(ks_ + 32, kd_ + 1024);                  \
    }                                                                            \
    if (w == 0) {                                                                \
      const u16* ks_ = Kb + (size_t)(BB * NN + srow) * DD + kpos_;               \
      char* kd_ = sb_ + 16384 + 16 * 2048;                                       \
      gload_lds16(ks_, kd_); gload_lds16(ks_ + 32, kd_ + 1024);                  \
    }                                                                            \
  } while (0)

__global__ __launch_bounds__(512)
void fused_attn(const u16* __restrict__ Qb, const u16* __restrict__ Kb,
                const u16* __restrict__ Vt, u16* __restrict__ O)
{
  extern __shared__ char smem[];
  const int tid = threadIdx.x;
  const int l = tid & 63;
  const int w = tid >> 6;

  // XCD pairing: consecutive hw ids round-robin XCDs; map so lin&7 == xcd chunk
  // holds 16 whole batches (both q-tiles) -> second K/V reader hits that XCD's L2.
  const int lin = blockIdx.y * 2 + blockIdx.x;          // grid (2, BB)
  const int sw  = (lin & 7) * 32 + (lin >> 3);          // bijective on [0,256)
  const int b   = sw >> 1;
  const int qt  = sw & 1;

  const int jj = (l < 32) ? l : (l ^ 2);
  const int srow = jj >> 2;
  const int scol = (jj & 3) * 8;
  const int fbase = (((l & 15) * 64) + ((l >> 4) * 16)) ^ (((l >> 3) & 1) << 5);
  const int fr = l & 15, g4 = l >> 4;

  const u16* Qrow0 = Qb + ((size_t)b * NN + qt * 128) * DD;

  // ---- phase A: S = Q K^T (double-buffered, counted vmcnt) ----
  f32x4 accS[17];
  #pragma unroll
  for (int i = 0; i < 17; ++i) accS[i] = (f32x4){0.f, 0.f, 0.f, 0.f};

  STAGE_A(0, 0);

  for (int kt = 0; kt < 12; ++kt) {
    const int s = kt & 1, ss = s ^ 1;
    BAR();                               // prev compute done -> safe to overwrite ss
    STAGE_A((kt < 11) ? (kt + 1) : 11, ss);
    if (w == 0) { asm volatile("s_waitcnt vmcnt(8)" ::: "memory"); }
    else        { asm volatile("s_waitcnt vmcnt(6)" ::: "memory"); }
    BAR();                               // slot s globally staged

    const char* base = smem + s * ASLOT;
    short8 aq0 = *(const short8*)(base + (w * 2 + 0) * 1024 + fbase);
    short8 aq1 = *(const short8*)(base + (w * 2 + 1) * 1024 + fbase);
    #pragma unroll
    for (int ni = 0; ni < 17; ++ni) {
      short8 bk0 = *(const short8*)(base + 16384 + (ni * 2 + 0) * 1024 + fbase);
      short8 bk1 = *(const short8*)(base + 16384 + (ni * 2 + 1) * 1024 + fbase);
      accS[ni] = __builtin_amdgcn_mfma_f32_16x16x32_bf16(aq0, bk0, accS[ni], 0, 0, 0);
      accS[ni] = __builtin_amdgcn_mfma_f32_16x16x32_bf16(aq1, bk1, accS[ni], 0, 0, 0);
    }
  }

  // ---- softmax: register-only reduction first (overlaps the drain) ----
  const float scl = 0.03608439182435161f;  // 768^-0.5
  #pragma unroll
  for (int ni = 0; ni < 17; ++ni)
    #pragma unroll
    for (int r = 0; r < 4; ++r) accS[ni][r] *= scl;
  if (fr >= 8) {  // mask pad keys t = 264..271
    #pragma unroll
    for (int r = 0; r < 4; ++r) accS[16][r] = -1e30f;
  }
  float inv4[4];
  #pragma unroll
  for (int r = 0; r < 4; ++r) {
    float mv = -1e30f;
    #pragma unroll
    for (int ni = 0; ni < 17; ++ni) mv = fmaxf(mv, accS[ni][r]);
    #pragma unroll
    for (int off = 8; off; off >>= 1) mv = fmaxf(mv, __shfl_xor(mv, off));
    float sum = 0.f;
    #pragma unroll
    for (int ni = 0; ni < 17; ++ni) {
      float e = __expf(accS[ni][r] - mv);
      accS[ni][r] = e;
      sum += e;
    }
    #pragma unroll
    for (int off = 8; off; off >>= 1) sum += __shfl_xor(sum, off);
    inv4[r] = 1.f / sum;
  }

  VMW0(); BAR();   // drain dead stages; all waves past A-reads before P overwrites slots

  #pragma unroll
  for (int r = 0; r < 4; ++r) {
    const int q = w * 16 + g4 * 4 + r;
    char* prow = smem + q * PPITCH;
    #pragma unroll
    for (int ni = 0; ni < 17; ++ni)
      *(u16*)(prow + (ni * 16 + fr) * 2) = f2bf(accS[ni][r] * inv4[r]);
    *(u16*)(prow + (272 + fr) * 2) = 0;  // zero t 272..287
  }
  __syncthreads();

  // ---- phase B: O = P @ V^T (dbuf, counted vmcnt(3)) ----
  const u16* Vtb = Vt + (size_t)b * DD * TP;
  const int qh = w >> 2, dq = w & 3;
  f32x4 accO[4][6];

  { // prologue: stage (pass 0, chunk 0) into slot 0
    #pragma unroll
    for (int rep = 0; rep < 3; ++rep) {
      const int rg = w * 3 + rep;
      const u16* src = Vtb + (size_t)(rg * 16 + srow) * TP + scol;
      gload_lds16(src, smem + VOFF + rg * 1024);
    }
  }

  int cur = 0;
  for (int p = 0; p < 2; ++p) {
    #pragma unroll
    for (int mi = 0; mi < 4; ++mi)
      #pragma unroll
      for (int nj = 0; nj < 6; ++nj) accO[mi][nj] = (f32x4){0.f, 0.f, 0.f, 0.f};

    for (int tc = 0; tc < 9; ++tc) {
      int np = p, nc = tc + 1;
      if (nc == 9) { np = p + 1; nc = 0; }
      if (np == 2) { np = 1; nc = 8; }   // dead stage on final iteration
      BAR();                              // prior compute consumed slot cur^1
      {
        #pragma unroll
        for (int rep = 0; rep < 3; ++rep) {
          const int rg = w * 3 + rep;
          const u16* src = Vtb + (size_t)(np * 384 + rg * 16 + srow) * TP + nc * 32 + scol;
          gload_lds16(src, smem + VOFF + (cur ^ 1) * VSLOT + rg * 1024);
        }
      }
      VMW3();                             // slot cur's 3 loads complete
      BAR();

      short8 pa[4], vb[6];
      #pragma unroll
      for (int mi = 0; mi < 4; ++mi)
        pa[mi] = *(const short8*)(smem +
                   (qh * 64 + mi * 16 + fr) * PPITCH + tc * 64 + g4 * 16);
      #pragma unroll
      for (int nj = 0; nj < 6; ++nj)
        vb[nj] = *(const short8*)(smem + VOFF + cur * VSLOT + (dq * 6 + nj) * 1024 + fbase);
      __builtin_amdgcn_s_setprio(1);
      #pragma unroll
      for (int mi = 0; mi < 4; ++mi)
        #pragma unroll
        for (int nj = 0; nj < 6; ++nj)
          accO[mi][nj] = __builtin_amdgcn_mfma_f32_16x16x32_bf16(pa[mi], vb[nj], accO[mi][nj], 0, 0, 0);
      __builtin_amdgcn_s_setprio(0);
      cur ^= 1;
    }

    u16* Ob = O + ((size_t)b * NN + qt * 128 + qh * 64) * DD + p * 384 + dq * 96;
    #pragma unroll
    for (int mi = 0; mi < 4; ++mi)
      #pragma unroll
      for (int nj = 0; nj < 6; ++nj)
        #pragma unroll
        for (int r = 0; r < 4; ++r)
          Ob[(size_t)(mi * 16 + g4 * 4 + r) * DD + nj * 16 + fr] = f2bf(accO[mi][nj][r]);
  }
}

// ---------------- launch ----------------
// Order: conv_x, conv_w -> G1 -> transpose_v -> fused_attn -> G3.
// d_out (100.66 MB): Ab [0,50.72M) live conv_x->G1; W^T(q,k,v) [97.12M,100.66M)
//   live conv_w->G1; Vt [0,62.91M) live transpose_v->fused (over dead Ab);
//   all dead before G3 writes d_out.
// ws (high-water 153.35 MB, proven safe): Qb@0, Kb@50.72M (live G1->fused);
//   Vb@101.45M (live G1->transpose_v); O@101.45M over dead Vb (live fused->G3);
//   Wot@152.17M (live conv_w->G3).

extern "C" void kernel_launch(void* const* d_in, const int* in_sizes, int n_in,
                              void* d_out, int out_size, void* d_ws, size_t ws_size,
                              hipStream_t stream) {
  const float* x   = (const float*)d_in[0];
  const float* mem = (const float*)d_in[1];
  const float* Wq  = (const float*)d_in[2];
  const float* bq  = (const float*)d_in[3];
  const float* Wk  = (const float*)d_in[4];
  const float* bk  = (const float*)d_in[5];
  const float* Wv  = (const float*)d_in[6];
  const float* bv  = (const float*)d_in[7];
  const float* Wo  = (const float*)d_in[8];
  const float* bo  = (const float*)d_in[9];
  float* out = (float*)d_out;
  (void)ws_size; (void)in_sizes; (void)n_in; (void)out_size;

  const size_t QKV_B = (size_t)AROWS2 * DD * 2;        // 50,724,864
  char* wsb = (char*)d_ws;
  u16* Qb  = (u16*)(wsb);
  u16* Kb  = (u16*)(wsb + QKV_B);
  u16* Vb  = (u16*)(wsb + 2 * QKV_B);
  u16* O   = (u16*)(wsb + 2 * QKV_B);                  // over Vb (dead after transpose_v)
  u16* Wot = (u16*)(wsb + 3 * QKV_B);

  u16*   Ab  = (u16*)d_out;                            // live conv_x -> G1
  u16*   Vt  = (u16*)d_out;                            // live transpose_v -> fused (over dead Ab)
  u16*   Wqt = (u16*)((char*)d_out + 97124352);        // live conv_w -> G1
  u16*   Wkt = Wqt + (size_t)DD * DD;
  u16*   Wvt = Wkt + (size_t)DD * DD;

  conv_x<<<2048, 256, 0, stream>>>(x, mem, Ab);
  conv_w<<<1024, 256, 0, stream>>>(Wq, Wk, Wv, Wo, Wqt, Wkt, Wvt, Wot);

  // G1: QKV projection  [33024 x 2304] = Ab @ [Wqt|Wkt|Wvt]^T  (+bias, -> bf16)
  gemm256<0><<<dim3(9, 129), 512, 131072, stream>>>(
      Ab, Wqt, Wkt, Wvt, bq, bk, bv, Qb, Kb, Vb, nullptr, DD / 64);

  // Vt[b][d][t] (writes d_out over dead Ab)
  transpose_v<<<dim3(12, 5, BB), 256, 0, stream>>>(Vb, Vt);

  // fused attention: Qb, Kb, Vt -> O (bf16 [32768][768], over dead Vb)
  fused_attn<<<dim3(2, BB), 512, 124928, stream>>>(Qb, Kb, Vt, O);

  // G3: out = O @ Wot^T + bo  (fp32)
  gemm256<1><<<dim3(3, 128), 512, 131072, stream>>>(
      O, Wot, nullptr, nullptr, bo, nullptr, nullptr,
      nullptr, nullptr, nullptr, out, DD / 64);
}

// Round 9
// 350.497 us; speedup vs baseline: 1.0477x; 1.0163x over previous
//
#include <hip/hip_runtime.h>
#include <hip/hip_bf16.h>

typedef __attribute__((ext_vector_type(4))) float f32x4;
typedef __attribute__((ext_vector_type(8))) short short8;
typedef __attribute__((ext_vector_type(4))) unsigned short us4;
typedef unsigned short u16;

#define DEVI __device__ __forceinline__

#define BB 128      // batches
#define NN 256      // input patches per batch
#define MMEM 8      // memory tokens
#define DD 768      // embed dim
#define TT 264      // N + M
#define TP 320      // Vt col padding (zeros in cols 264..319)
#define AROWS2 33024  // 129*256: rows for the 256-tile GEMMs (x .. memory .. zero pad)

DEVI u16 f2bf(float f) {
  __hip_bfloat16 b = __float2bfloat16(f);
  u16 u; __builtin_memcpy(&u, &b, 2); return u;
}

DEVI void gload_lds16(const void* g, void* l) {
  __builtin_amdgcn_global_load_lds((const __attribute__((address_space(1))) void*)g,
                                   (__attribute__((address_space(3))) void*)l, 16, 0, 0);
}

// ---------------- conversion kernels ----------------

__global__ __launch_bounds__(256)
void conv_x(const float* __restrict__ x, const float* __restrict__ mem, u16* __restrict__ Ab) {
  const long total4 = (long)AROWS2 * DD / 4;
  for (long i = (long)blockIdx.x * blockDim.x + threadIdx.x; i < total4;
       i += (long)gridDim.x * blockDim.x) {
    long e = i * 4;
    int row = (int)(e / DD);
    int cb  = (int)(e % DD);
    f32x4 v = {0.f, 0.f, 0.f, 0.f};
    if (row < BB * NN)             v = *(const f32x4*)(x   + (size_t)row * DD + cb);
    else if (row < BB * NN + MMEM) v = *(const f32x4*)(mem + (size_t)(row - BB * NN) * DD + cb);
    us4 o = {f2bf(v[0]), f2bf(v[1]), f2bf(v[2]), f2bf(v[3])};
    *(us4*)(Ab + e) = o;
  }
}

__global__ __launch_bounds__(256)
void conv_w(const float* __restrict__ Wq, const float* __restrict__ Wk,
            const float* __restrict__ Wv, const float* __restrict__ Wo,
            u16* __restrict__ Wqt, u16* __restrict__ Wkt,
            u16* __restrict__ Wvt, u16* __restrict__ Wot) {
  const int total = 4 * DD * DD;
  for (int i = blockIdx.x * blockDim.x + threadIdx.x; i < total;
       i += gridDim.x * blockDim.x) {
    int mat = i / (DD * DD), rem = i % (DD * DD);
    int j = rem / DD, d = rem % DD;
    const float* W = (mat == 0) ? Wq : (mat == 1) ? Wk : (mat == 2) ? Wv : Wo;
    u16* Wt = (mat == 0) ? Wqt : (mat == 1) ? Wkt : (mat == 2) ? Wvt : Wot;
    Wt[(size_t)j * DD + d] = f2bf(W[(size_t)d * DD + j]);
  }
}

// ================= 256x256 8-wave B^T GEMM (K = 768) =================
// ROUND-9: software-pipelined 4-phase loop. Round-4/8's loop issued each phase's
// ds_reads in the SAME phase as the consuming MFMA ([read -> lgkm(0) -> MFMA]
// serialized; MFMA 2483 cyc + LDS 1536 cyc ADD -> 33% MfmaUtil). Now each phase
// reads the NEXT phase's fragments, so the (compiler-inserted, counted) lgkm wait
// before each MFMA covers reads that had a full MFMA window to complete.
// Quadrant order Q00,Q10,Q01,Q11 makes fa0/fb0 dead by ph2 -> ph3 re-reads the
// NEXT K-tile's A0/B0 into the same registers (no extra VGPR, no unroll).
// 3 barriers + 3x vmcnt(2) per K-tile (was 8 barriers + 3x vmcnt(4)).
// In-flight ledger (loads, 2 per STG; stage order A0,B0,A1,B1 of tile g+1):
//   ph0 top: {A1(g),B1(g)}=4      -> vmcnt(2) retires A1(g); RD fa1(slot s) safe
//   ph1 top: {B1(g),A0(g+1)}=4    -> vmcnt(2) retires B1(g); RD fb1(slot s) safe
//   ph2: no reads, no barrier (STG_A1 targets slot ss; old-data reads of that
//        region completed >=2 barriers earlier - per-region WAR trace)
//   ph3 top: {A0,B0,A1(g+1)}=6    -> vmcnt(2) retires A0,B0(g+1); RD fa0/fb0(ss) safe
// T1 XCD swizzle, T2 subtile swizzle (0 conflicts), T5 setprio retained.

#define BAR()    __builtin_amdgcn_s_barrier()
#define CFENCE() asm volatile("" ::: "memory")
#define LGKM0()  asm volatile("s_waitcnt lgkmcnt(0)" ::: "memory")
#define VM2()    asm volatile("s_waitcnt vmcnt(2)" ::: "memory")
#define VMW0()   asm volatile("s_waitcnt vmcnt(0)" ::: "memory")
#define VMW3()   asm volatile("s_waitcnt vmcnt(3)" ::: "memory")

#define STG(gb, isB, ss, rg, kt) do {                                          \
    const u16* _s = (gb) + (size_t)((rg) * 16 + srow) * DD + (kt) * 64 + scol; \
    char* _d = smem + (ss) * 65536 + (isB) * 32768 + (rg) * 2048;              \
    gload_lds16(_s, _d);                                                       \
    gload_lds16(_s + 32, _d + 1024);                                           \
  } while (0)

#define STG_A0(ss, kt) STG(Ab, 0, ss, ((w & 3) | ((w & 4) << 1)), kt)
#define STG_B0(ss, kt) STG(Bb, 1, ss, ((w & 1) | ((w & 6) << 1)), kt)
#define STG_A1(ss, kt) STG(Ab, 0, ss, (((w & 3) | ((w & 4) << 1)) + 4), kt)
#define STG_B1(ss, kt) STG(Bb, 1, ss, (((w & 1) | ((w & 6) << 1)) + 2), kt)

#define RD_A(dst, s, QM)                                                          \
  _Pragma("unroll") for (int mi = 0; mi < 4; ++mi)                                \
  _Pragma("unroll") for (int ks = 0; ks < 2; ++ks)                                \
    dst[mi][ks] = *(const short8*)(smem + (s) * 65536 +                           \
                    ((wm * 8 + (QM) * 4 + mi) * 2 + ks) * 1024 + fbase);

#define RD_B(dst, s, QN)                                                          \
  _Pragma("unroll") for (int ni = 0; ni < 2; ++ni)                                \
  _Pragma("unroll") for (int ks = 0; ks < 2; ++ks)                                \
    dst[ni][ks] = *(const short8*)(smem + (s) * 65536 + 32768 +                   \
                    ((wn * 4 + (QN) * 2 + ni) * 2 + ks) * 1024 + fbase);

#define MM(FA, FB, QM, QN)                                                        \
  _Pragma("unroll") for (int mi = 0; mi < 4; ++mi)                                \
  _Pragma("unroll") for (int ni = 0; ni < 2; ++ni)                                \
  _Pragma("unroll") for (int ks = 0; ks < 2; ++ks)                                \
    acc[(QM)*4+mi][(QN)*2+ni] = __builtin_amdgcn_mfma_f32_16x16x32_bf16(          \
        FA[mi][ks], FB[ni][ks], acc[(QM)*4+mi][(QN)*2+ni], 0, 0, 0);

template<int MODE>
__global__ __launch_bounds__(512)
void gemm256(const u16* __restrict__ A, const u16* __restrict__ Bq,
             const u16* __restrict__ Bk, const u16* __restrict__ Bv,
             const float* __restrict__ b0, const float* __restrict__ b1,
             const float* __restrict__ b2,
             u16* __restrict__ Oq, u16* __restrict__ Ok, u16* __restrict__ Ov,
             float* __restrict__ FO, int NT)
{
  extern __shared__ char smem[];
  const int tid = threadIdx.x;
  const int l = tid & 63;
  const int w = tid >> 6;
  const int wm = w >> 2, wn = w & 3;

  // T1: bijective XCD swizzle (m204)
  const int nwg = gridDim.x * gridDim.y;
  const int lin = blockIdx.y * gridDim.x + blockIdx.x;
  const int qq = nwg >> 3, rr = nwg & 7;
  const int xcd = lin & 7, idx = lin >> 3;
  const int wg = (xcd < rr ? xcd * (qq + 1) : rr * (qq + 1) + (xcd - rr) * qq) + idx;
  const int tn = wg % gridDim.x, tm = wg / gridDim.x;

  const u16* Ab = A + (size_t)tm * 256 * DD;
  const u16* Bb;
  int matsel = 0;
  if constexpr (MODE == 0) {
    matsel = tn / 3;
    const u16* Wp = (matsel == 0) ? Bq : (matsel == 1) ? Bk : Bv;
    Bb = Wp + (size_t)(tn % 3) * 256 * DD;
  } else {
    Bb = Bq + (size_t)tn * 256 * DD;
  }

  const int jj = (l < 32) ? l : (l ^ 2);
  const int srow = jj >> 2;
  const int scol = (jj & 3) * 8;
  const int fbase = (((l & 15) * 64) + ((l >> 4) * 16)) ^ (((l >> 3) & 1) << 5);

  f32x4 acc[8][4];
  #pragma unroll
  for (int i = 0; i < 8; ++i)
    #pragma unroll
    for (int jx = 0; jx < 4; ++jx) acc[i][jx] = (f32x4){0.f, 0.f, 0.f, 0.f};

  short8 fa0[4][2], fa1[4][2], fb0[2][2], fb1[2][2];

  // prologue: stage K-tile 0 -> slot 0; drain; read ph0 fragments
  STG_A0(0, 0); STG_B0(0, 0); STG_A1(0, 0); STG_B1(0, 0);
  VMW0(); BAR(); CFENCE();
  RD_A(fa0, 0, 0); RD_B(fb0, 0, 0);

  for (int g = 0; g < NT; ++g) {
    const int s = g & 1, ss = s ^ 1;
    const int st = (g + 1 < NT) ? (g + 1) : (NT - 1);  // last iter re-stages (dead)

    // ph0: MM Q00(fa0,fb0) | RD fa1 (slot s) | stage A0(g+1)
    VM2(); BAR(); CFENCE();
    RD_A(fa1, s, 1);
    STG_A0(ss, st);
    __builtin_amdgcn_s_setprio(1); MM(fa0, fb0, 0, 0); __builtin_amdgcn_s_setprio(0);

    // ph1: MM Q10(fa1,fb0) | RD fb1 (slot s) | stage B0(g+1)
    VM2(); BAR(); CFENCE();
    RD_B(fb1, s, 1);
    STG_B0(ss, st);
    __builtin_amdgcn_s_setprio(1); MM(fa1, fb0, 1, 0); __builtin_amdgcn_s_setprio(0);

    // ph2: MM Q01(fa0,fb1) | no reads, no barrier | stage A1(g+1)
    STG_A1(ss, st);
    __builtin_amdgcn_s_setprio(1); MM(fa0, fb1, 0, 1); __builtin_amdgcn_s_setprio(0);

    // ph3: MM Q11(fa1,fb1) | RD fa0,fb0 (slot ss = tile g+1) | stage B1(g+1)
    VM2(); BAR(); CFENCE();
    RD_A(fa0, ss, 0); RD_B(fb0, ss, 0);
    STG_B1(ss, st);
    __builtin_amdgcn_s_setprio(1); MM(fa1, fb1, 1, 1); __builtin_amdgcn_s_setprio(0);
  }

  const int fr = l & 15, fro = (l >> 4) * 4;
  if constexpr (MODE == 0) {
    const float* bias = (matsel == 0) ? b0 : (matsel == 1) ? b1 : b2;
    u16* ob = (matsel == 0) ? Oq : (matsel == 1) ? Ok : Ov;
    const int cb = (tn % 3) * 256 + wn * 64;
    const size_t rb = (size_t)tm * 256 + wm * 128;
    #pragma unroll
    for (int MI = 0; MI < 8; ++MI)
      #pragma unroll
      for (int NI = 0; NI < 4; ++NI) {
        const int col = cb + NI * 16 + fr;
        const float bvv = bias[col];
        #pragma unroll
        for (int r = 0; r < 4; ++r)
          ob[(rb + MI * 16 + fro + r) * DD + col] = f2bf(acc[MI][NI][r] + bvv);
      }
  } else {
    const int cb = tn * 256 + wn * 64;
    const size_t rb = (size_t)tm * 256 + wm * 128;
    #pragma unroll
    for (int MI = 0; MI < 8; ++MI)
      #pragma unroll
      for (int NI = 0; NI < 4; ++NI) {
        const int col = cb + NI * 16 + fr;
        const float bvv = b0[col];
        #pragma unroll
        for (int r = 0; r < 4; ++r)
          FO[(rb + MI * 16 + fro + r) * DD + col] = acc[MI][NI][r] + bvv;
      }
  }
}

// ---------------- V transpose: Vt[b][d][t] (t padded to 320 with zeros) ----------------

__global__ __launch_bounds__(256)
void transpose_v(const u16* __restrict__ V, u16* __restrict__ Vt) {
  __shared__ u16 ls[64 * 66];
  const int b = blockIdx.z;
  const int d0 = blockIdx.x * 64;
  const int t0 = blockIdx.y * 64;
  const int tid = threadIdx.x;
  #pragma unroll
  for (int q = 0; q < 2; ++q) {
    const int idx = q * 256 + tid;
    const int tr = idx >> 3;
    const int dg = (idx & 7) * 8;
    const int t = t0 + tr;
    short8 v = (short8)(short)0;
    if (t < NN)       v = *(const short8*)(V + ((size_t)b * NN + t) * DD + d0 + dg);
    else if (t < TT)  v = *(const short8*)(V + (size_t)(BB * NN + t - NN) * DD + d0 + dg);
    #pragma unroll
    for (int e = 0; e < 8; ++e) ls[tr * 66 + dg + e] = (u16)v[e];
  }
  __syncthreads();
  #pragma unroll
  for (int q = 0; q < 2; ++q) {
    const int idx = q * 256 + tid;
    const int dr = idx >> 3;
    const int tg = (idx & 7) * 8;
    short8 v;
    #pragma unroll
    for (int e = 0; e < 8; ++e) v[e] = (short)ls[(tg + e) * 66 + dr];
    *(short8*)(Vt + ((size_t)b * DD + d0 + dr) * TP + t0 + tg) = v;
  }
}

// ================= fused attention (round-8 structure, unchanged) =================

#define ASLOT  51200
#define PPITCH 592
#define VOFF   75776
#define VSLOT  24576

#define STAGE_A(kt, slot) do {                                                   \
    const int kpos_ = (kt) * 64 + scol;                                          \
    char* sb_ = smem + (slot) * ASLOT;                                           \
    const u16* qs_ = Qrow0 + (size_t)(w * 16 + srow) * DD + kpos_;               \
    gload_lds16(qs_, sb_ + w * 2048);                                            \
    gload_lds16(qs_ + 32, sb_ + w * 2048 + 1024);                                \
    _Pragma("unroll") for (int rep_ = 0; rep_ < 2; ++rep_) {                     \
      const int rg_ = w + rep_ * 8;                                              \
      const int kr_ = rg_ * 16 + srow;                                           \
      const int grow_ = (kr_ < NN) ? (b * NN + kr_) : (BB * NN + kr_ - NN);      \
      const u16* ks_ = Kb + (size_t)grow_ * DD + kpos_;                          \
      char* kd_ = sb_ + 16384 + rg_ * 2048;                                      \
      gload_lds16(ks_, kd_); gload_lds16(ks_ + 32, kd_ + 1024);                  \
    }                                                                            \
    if (w == 0) {                                                                \
      const u16* ks_ = Kb + (size_t)(BB * NN + srow) * DD + kpos_;               \
      char* kd_ = sb_ + 16384 + 16 * 2048;                                       \
      gload_lds16(ks_, kd_); gload_lds16(ks_ + 32, kd_ + 1024);                  \
    }                                                                            \
  } while (0)

__global__ __launch_bounds__(512)
void fused_attn(const u16* __restrict__ Qb, const u16* __restrict__ Kb,
                const u16* __restrict__ Vt, u16* __restrict__ O)
{
  extern __shared__ char smem[];
  const int tid = threadIdx.x;
  const int l = tid & 63;
  const int w = tid >> 6;

  const int lin = blockIdx.y * 2 + blockIdx.x;          // grid (2, BB)
  const int sw  = (lin & 7) * 32 + (lin >> 3);          // bijective on [0,256)
  const int b   = sw >> 1;
  const int qt  = sw & 1;

  const int jj = (l < 32) ? l : (l ^ 2);
  const int srow = jj >> 2;
  const int scol = (jj & 3) * 8;
  const int fbase = (((l & 15) * 64) + ((l >> 4) * 16)) ^ (((l >> 3) & 1) << 5);
  const int fr = l & 15, g4 = l >> 4;

  const u16* Qrow0 = Qb + ((size_t)b * NN + qt * 128) * DD;

  f32x4 accS[17];
  #pragma unroll
  for (int i = 0; i < 17; ++i) accS[i] = (f32x4){0.f, 0.f, 0.f, 0.f};

  STAGE_A(0, 0);

  for (int kt = 0; kt < 12; ++kt) {
    const int s = kt & 1, ss = s ^ 1;
    BAR();
    STAGE_A((kt < 11) ? (kt + 1) : 11, ss);
    if (w == 0) { asm volatile("s_waitcnt vmcnt(8)" ::: "memory"); }
    else        { asm volatile("s_waitcnt vmcnt(6)" ::: "memory"); }
    BAR();

    const char* base = smem + s * ASLOT;
    short8 aq0 = *(const short8*)(base + (w * 2 + 0) * 1024 + fbase);
    short8 aq1 = *(const short8*)(base + (w * 2 + 1) * 1024 + fbase);
    #pragma unroll
    for (int ni = 0; ni < 17; ++ni) {
      short8 bk0 = *(const short8*)(base + 16384 + (ni * 2 + 0) * 1024 + fbase);
      short8 bk1 = *(const short8*)(base + 16384 + (ni * 2 + 1) * 1024 + fbase);
      accS[ni] = __builtin_amdgcn_mfma_f32_16x16x32_bf16(aq0, bk0, accS[ni], 0, 0, 0);
      accS[ni] = __builtin_amdgcn_mfma_f32_16x16x32_bf16(aq1, bk1, accS[ni], 0, 0, 0);
    }
  }

  const float scl = 0.03608439182435161f;  // 768^-0.5
  #pragma unroll
  for (int ni = 0; ni < 17; ++ni)
    #pragma unroll
    for (int r = 0; r < 4; ++r) accS[ni][r] *= scl;
  if (fr >= 8) {
    #pragma unroll
    for (int r = 0; r < 4; ++r) accS[16][r] = -1e30f;
  }
  float inv4[4];
  #pragma unroll
  for (int r = 0; r < 4; ++r) {
    float mv = -1e30f;
    #pragma unroll
    for (int ni = 0; ni < 17; ++ni) mv = fmaxf(mv, accS[ni][r]);
    #pragma unroll
    for (int off = 8; off; off >>= 1) mv = fmaxf(mv, __shfl_xor(mv, off));
    float sum = 0.f;
    #pragma unroll
    for (int ni = 0; ni < 17; ++ni) {
      float e = __expf(accS[ni][r] - mv);
      accS[ni][r] = e;
      sum += e;
    }
    #pragma unroll
    for (int off = 8; off; off >>= 1) sum += __shfl_xor(sum, off);
    inv4[r] = 1.f / sum;
  }

  VMW0(); BAR();

  #pragma unroll
  for (int r = 0; r < 4; ++r) {
    const int q = w * 16 + g4 * 4 + r;
    char* prow = smem + q * PPITCH;
    #pragma unroll
    for (int ni = 0; ni < 17; ++ni)
      *(u16*)(prow + (ni * 16 + fr) * 2) = f2bf(accS[ni][r] * inv4[r]);
    *(u16*)(prow + (272 + fr) * 2) = 0;
  }
  __syncthreads();

  const u16* Vtb = Vt + (size_t)b * DD * TP;
  const int qh = w >> 2, dq = w & 3;
  f32x4 accO[4][6];

  {
    #pragma unroll
    for (int rep = 0; rep < 3; ++rep) {
      const int rg = w * 3 + rep;
      const u16* src = Vtb + (size_t)(rg * 16 + srow) * TP + scol;
      gload_lds16(src, smem + VOFF + rg * 1024);
    }
  }

  int cur = 0;
  for (int p = 0; p < 2; ++p) {
    #pragma unroll
    for (int mi = 0; mi < 4; ++mi)
      #pragma unroll
      for (int nj = 0; nj < 6; ++nj) accO[mi][nj] = (f32x4){0.f, 0.f, 0.f, 0.f};

    for (int tc = 0; tc < 9; ++tc) {
      int np = p, nc = tc + 1;
      if (nc == 9) { np = p + 1; nc = 0; }
      if (np == 2) { np = 1; nc = 8; }
      BAR();
      {
        #pragma unroll
        for (int rep = 0; rep < 3; ++rep) {
          const int rg = w * 3 + rep;
          const u16* src = Vtb + (size_t)(np * 384 + rg * 16 + srow) * TP + nc * 32 + scol;
          gload_lds16(src, smem + VOFF + (cur ^ 1) * VSLOT + rg * 1024);
        }
      }
      VMW3();
      BAR();

      short8 pa[4], vb[6];
      #pragma unroll
      for (int mi = 0; mi < 4; ++mi)
        pa[mi] = *(const short8*)(smem +
                   (qh * 64 + mi * 16 + fr) * PPITCH + tc * 64 + g4 * 16);
      #pragma unroll
      for (int nj = 0; nj < 6; ++nj)
        vb[nj] = *(const short8*)(smem + VOFF + cur * VSLOT + (dq * 6 + nj) * 1024 + fbase);
      __builtin_amdgcn_s_setprio(1);
      #pragma unroll
      for (int mi = 0; mi < 4; ++mi)
        #pragma unroll
        for (int nj = 0; nj < 6; ++nj)
          accO[mi][nj] = __builtin_amdgcn_mfma_f32_16x16x32_bf16(pa[mi], vb[nj], accO[mi][nj], 0, 0, 0);
      __builtin_amdgcn_s_setprio(0);
      cur ^= 1;
    }

    u16* Ob = O + ((size_t)b * NN + qt * 128 + qh * 64) * DD + p * 384 + dq * 96;
    #pragma unroll
    for (int mi = 0; mi < 4; ++mi)
      #pragma unroll
      for (int nj = 0; nj < 6; ++nj)
        #pragma unroll
        for (int r = 0; r < 4; ++r)
          Ob[(size_t)(mi * 16 + g4 * 4 + r) * DD + nj * 16 + fr] = f2bf(accO[mi][nj][r]);
  }
}

// ---------------- launch ----------------
// Order: conv_x, conv_w -> G1 -> transpose_v -> fused_attn -> G3.
// d_out (100.66 MB): Ab [0,50.72M) live conv_x->G1; W^T(q,k,v) [97.12M,100.66M)
//   live conv_w->G1; Vt [0,62.91M) live transpose_v->fused (over dead Ab);
//   all dead before G3 writes d_out.
// ws (high-water 153.35 MB, proven safe): Qb@0, Kb@50.72M (live G1->fused);
//   Vb@101.45M (live G1->transpose_v); O@101.45M over dead Vb (live fused->G3);
//   Wot@152.17M (live conv_w->G3).

extern "C" void kernel_launch(void* const* d_in, const int* in_sizes, int n_in,
                              void* d_out, int out_size, void* d_ws, size_t ws_size,
                              hipStream_t stream) {
  const float* x   = (const float*)d_in[0];
  const float* mem = (const float*)d_in[1];
  const float* Wq  = (const float*)d_in[2];
  const float* bq  = (const float*)d_in[3];
  const float* Wk  = (const float*)d_in[4];
  const float* bk  = (const float*)d_in[5];
  const float* Wv  = (const float*)d_in[6];
  const float* bv  = (const float*)d_in[7];
  const float* Wo  = (const float*)d_in[8];
  const float* bo  = (const float*)d_in[9];
  float* out = (float*)d_out;
  (void)ws_size; (void)in_sizes; (void)n_in; (void)out_size;

  const size_t QKV_B = (size_t)AROWS2 * DD * 2;        // 50,724,864
  char* wsb = (char*)d_ws;
  u16* Qb  = (u16*)(wsb);
  u16* Kb  = (u16*)(wsb + QKV_B);
  u16* Vb  = (u16*)(wsb + 2 * QKV_B);
  u16* O   = (u16*)(wsb + 2 * QKV_B);                  // over Vb (dead after transpose_v)
  u16* Wot = (u16*)(wsb + 3 * QKV_B);

  u16*   Ab  = (u16*)d_out;                            // live conv_x -> G1
  u16*   Vt  = (u16*)d_out;                            // live transpose_v -> fused (over dead Ab)
  u16*   Wqt = (u16*)((char*)d_out + 97124352);        // live conv_w -> G1
  u16*   Wkt = Wqt + (size_t)DD * DD;
  u16*   Wvt = Wkt + (size_t)DD * DD;

  conv_x<<<2048, 256, 0, stream>>>(x, mem, Ab);
  conv_w<<<1024, 256, 0, stream>>>(Wq, Wk, Wv, Wo, Wqt, Wkt, Wvt, Wot);

  // G1: QKV projection  [33024 x 2304] = Ab @ [Wqt|Wkt|Wvt]^T  (+bias, -> bf16)
  gemm256<0><<<dim3(9, 129), 512, 131072, stream>>>(
      Ab, Wqt, Wkt, Wvt, bq, bk, bv, Qb, Kb, Vb, nullptr, DD / 64);

  // Vt[b][d][t] (writes d_out over dead Ab)
  transpose_v<<<dim3(12, 5, BB), 256, 0, stream>>>(Vb, Vt);

  // fused attention: Qb, Kb, Vt -> O (bf16 [32768][768], over dead Vb)
  fused_attn<<<dim3(2, BB), 512, 124928, stream>>>(Qb, Kb, Vt, O);

  // G3: out = O @ Wot^T + bo  (fp32)
  gemm256<1><<<dim3(3, 128), 512, 131072, stream>>>(
      O, Wot, nullptr, nullptr, bo, nullptr, nullptr,
      nullptr, nullptr, nullptr, out, DD / 64);
}

// Round 10
// 333.011 us; speedup vs baseline: 1.1027x; 1.0525x over previous
//
#include <hip/hip_runtime.h>
#include <hip/hip_bf16.h>

typedef __attribute__((ext_vector_type(4))) float f32x4;
typedef __attribute__((ext_vector_type(8))) short short8;
typedef __attribute__((ext_vector_type(4))) unsigned short us4;
typedef unsigned short u16;

#define DEVI __device__ __forceinline__

#define BB 128      // batches
#define NN 256      // input patches per batch
#define MMEM 8      // memory tokens
#define DD 768      // embed dim
#define TT 264      // N + M
#define TP 320      // P/Vt col padding (zeros in cols 264..319)
#define SP 384      // S col padding (3 x 128 tiles)
#define AROWS2 33024  // 129*256: rows for the 256-tile GEMMs (x .. memory .. zero pad)

DEVI u16 f2bf(float f) {
  __hip_bfloat16 b = __float2bfloat16(f);
  u16 u; __builtin_memcpy(&u, &b, 2); return u;
}

DEVI void gload_lds16(const void* g, void* l) {
  __builtin_amdgcn_global_load_lds((const __attribute__((address_space(1))) void*)g,
                                   (__attribute__((address_space(3))) void*)l, 16, 0, 0);
}

// ---------------- conversion kernels ----------------

__global__ __launch_bounds__(256)
void conv_x(const float* __restrict__ x, const float* __restrict__ mem, u16* __restrict__ Ab) {
  const long total4 = (long)AROWS2 * DD / 4;
  for (long i = (long)blockIdx.x * blockDim.x + threadIdx.x; i < total4;
       i += (long)gridDim.x * blockDim.x) {
    long e = i * 4;
    int row = (int)(e / DD);
    int cb  = (int)(e % DD);
    f32x4 v = {0.f, 0.f, 0.f, 0.f};
    if (row < BB * NN)             v = *(const f32x4*)(x   + (size_t)row * DD + cb);
    else if (row < BB * NN + MMEM) v = *(const f32x4*)(mem + (size_t)(row - BB * NN) * DD + cb);
    us4 o = {f2bf(v[0]), f2bf(v[1]), f2bf(v[2]), f2bf(v[3])};
    *(us4*)(Ab + e) = o;
  }
}

__global__ __launch_bounds__(256)
void conv_w(const float* __restrict__ Wq, const float* __restrict__ Wk,
            const float* __restrict__ Wv, const float* __restrict__ Wo,
            u16* __restrict__ Wqt, u16* __restrict__ Wkt,
            u16* __restrict__ Wvt, u16* __restrict__ Wot) {
  const int total = 4 * DD * DD;
  for (int i = blockIdx.x * blockDim.x + threadIdx.x; i < total;
       i += gridDim.x * blockDim.x) {
    int mat = i / (DD * DD), rem = i % (DD * DD);
    int j = rem / DD, d = rem % DD;
    const float* W = (mat == 0) ? Wq : (mat == 1) ? Wk : (mat == 2) ? Wv : Wo;
    u16* Wt = (mat == 0) ? Wqt : (mat == 1) ? Wkt : (mat == 2) ? Wvt : Wot;
    Wt[(size_t)j * DD + d] = f2bf(W[(size_t)d * DD + j]);
  }
}

// ================= 256x256 8-wave pipelined B^T GEMM (round-9 loop) =================
// Software-pipelined 4-phase loop: each phase reads the NEXT phase's fragments so
// the compiler's counted lgkm waits cover reads that had a full MFMA window.
// Measured on G1: 147 -> ~115 us vs the phase-synchronous loop.
// MODE 0: QKV projection.  A=Ab[33024,768].  B by tn/3 among Wq/Wk/Wv^T.  bias, bf16 x3.
// MODE 1: out = A @ B^T + bias (fp32).  grid (tn, tm).
// MODE 2: O = P @ Vt^T per batch (strides TP).  grid (tn=3, z=128), tm=0.  bf16 out.

#define BAR()    __builtin_amdgcn_s_barrier()
#define CFENCE() asm volatile("" ::: "memory")
#define VM2()    asm volatile("s_waitcnt vmcnt(2)" ::: "memory")
#define VMW0()   asm volatile("s_waitcnt vmcnt(0)" ::: "memory")

#define STG(gb, ld, isB, ss, rg, kt) do {                                       \
    const u16* _s = (gb) + (size_t)((rg) * 16 + srow) * (ld) + (kt) * 64 + scol;\
    char* _d = smem + (ss) * 65536 + (isB) * 32768 + (rg) * 2048;               \
    gload_lds16(_s, _d);                                                        \
    gload_lds16(_s + 32, _d + 1024);                                            \
  } while (0)

#define STG_A0(ss, kt) STG(Ab, LDA, 0, ss, ((w & 3) | ((w & 4) << 1)), kt)
#define STG_B0(ss, kt) STG(Bb, LDB, 1, ss, ((w & 1) | ((w & 6) << 1)), kt)
#define STG_A1(ss, kt) STG(Ab, LDA, 0, ss, (((w & 3) | ((w & 4) << 1)) + 4), kt)
#define STG_B1(ss, kt) STG(Bb, LDB, 1, ss, (((w & 1) | ((w & 6) << 1)) + 2), kt)

#define RD_A(dst, s, QM)                                                          \
  _Pragma("unroll") for (int mi = 0; mi < 4; ++mi)                                \
  _Pragma("unroll") for (int ks = 0; ks < 2; ++ks)                                \
    dst[mi][ks] = *(const short8*)(smem + (s) * 65536 +                           \
                    ((wm * 8 + (QM) * 4 + mi) * 2 + ks) * 1024 + fbase);

#define RD_B(dst, s, QN)                                                          \
  _Pragma("unroll") for (int ni = 0; ni < 2; ++ni)                                \
  _Pragma("unroll") for (int ks = 0; ks < 2; ++ks)                                \
    dst[ni][ks] = *(const short8*)(smem + (s) * 65536 + 32768 +                   \
                    ((wn * 4 + (QN) * 2 + ni) * 2 + ks) * 1024 + fbase);

#define MM(FA, FB, QM, QN)                                                        \
  _Pragma("unroll") for (int mi = 0; mi < 4; ++mi)                                \
  _Pragma("unroll") for (int ni = 0; ni < 2; ++ni)                                \
  _Pragma("unroll") for (int ks = 0; ks < 2; ++ks)                                \
    acc[(QM)*4+mi][(QN)*2+ni] = __builtin_amdgcn_mfma_f32_16x16x32_bf16(          \
        FA[mi][ks], FB[ni][ks], acc[(QM)*4+mi][(QN)*2+ni], 0, 0, 0);

template<int MODE>
__global__ __launch_bounds__(512)
void gemm256(const u16* __restrict__ A, const u16* __restrict__ Bq,
             const u16* __restrict__ Bk, const u16* __restrict__ Bv,
             const float* __restrict__ b0, const float* __restrict__ b1,
             const float* __restrict__ b2,
             u16* __restrict__ Oq, u16* __restrict__ Ok, u16* __restrict__ Ov,
             float* __restrict__ FO, int NT)
{
  extern __shared__ char smem[];
  const int tid = threadIdx.x;
  const int l = tid & 63;
  const int w = tid >> 6;
  const int wm = w >> 2, wn = w & 3;

  constexpr int LDA = (MODE == 2) ? TP : DD;
  constexpr int LDB = (MODE == 2) ? TP : DD;

  // T1: bijective XCD swizzle (m204) over the flattened grid
  const int nwg = gridDim.x * gridDim.y;
  const int lin = blockIdx.y * gridDim.x + blockIdx.x;
  const int qq = nwg >> 3, rr = nwg & 7;
  const int xcd = lin & 7, idx = lin >> 3;
  const int wg = (xcd < rr ? xcd * (qq + 1) : rr * (qq + 1) + (xcd - rr) * qq) + idx;
  const int tn = wg % gridDim.x;
  const int tmz = wg / gridDim.x;   // tm (MODE 0/1) or batch z (MODE 2)

  const u16* Ab; const u16* Bb;
  int matsel = 0;
  if constexpr (MODE == 0) {
    Ab = A + (size_t)tmz * 256 * DD;
    matsel = tn / 3;
    const u16* Wp = (matsel == 0) ? Bq : (matsel == 1) ? Bk : Bv;
    Bb = Wp + (size_t)(tn % 3) * 256 * DD;
  } else if constexpr (MODE == 1) {
    Ab = A + (size_t)tmz * 256 * DD;
    Bb = Bq + (size_t)tn * 256 * DD;
  } else {
    Ab = A + (size_t)tmz * NN * TP;                      // P batch base (256 rows)
    Bb = Bq + ((size_t)tmz * DD + tn * 256) * TP;        // Vt batch base + d-panel
  }

  const int jj = (l < 32) ? l : (l ^ 2);
  const int srow = jj >> 2;
  const int scol = (jj & 3) * 8;
  const int fbase = (((l & 15) * 64) + ((l >> 4) * 16)) ^ (((l >> 3) & 1) << 5);

  f32x4 acc[8][4];
  #pragma unroll
  for (int i = 0; i < 8; ++i)
    #pragma unroll
    for (int jx = 0; jx < 4; ++jx) acc[i][jx] = (f32x4){0.f, 0.f, 0.f, 0.f};

  short8 fa0[4][2], fa1[4][2], fb0[2][2], fb1[2][2];

  // prologue: stage K-tile 0 -> slot 0; drain; read ph0 fragments
  STG_A0(0, 0); STG_B0(0, 0); STG_A1(0, 0); STG_B1(0, 0);
  VMW0(); BAR(); CFENCE();
  RD_A(fa0, 0, 0); RD_B(fb0, 0, 0);

  for (int g = 0; g < NT; ++g) {
    const int s = g & 1, ss = s ^ 1;
    const int st = (g + 1 < NT) ? (g + 1) : (NT - 1);  // last iter re-stages (dead)

    // ph0: MM Q00 | RD fa1 (slot s) | stage A0(g+1)
    VM2(); BAR(); CFENCE();
    RD_A(fa1, s, 1);
    STG_A0(ss, st);
    __builtin_amdgcn_s_setprio(1); MM(fa0, fb0, 0, 0); __builtin_amdgcn_s_setprio(0);

    // ph1: MM Q10 | RD fb1 (slot s) | stage B0(g+1)
    VM2(); BAR(); CFENCE();
    RD_B(fb1, s, 1);
    STG_B0(ss, st);
    __builtin_amdgcn_s_setprio(1); MM(fa1, fb0, 1, 0); __builtin_amdgcn_s_setprio(0);

    // ph2: MM Q01 | no reads, no barrier | stage A1(g+1)
    STG_A1(ss, st);
    __builtin_amdgcn_s_setprio(1); MM(fa0, fb1, 0, 1); __builtin_amdgcn_s_setprio(0);

    // ph3: MM Q11 | RD fa0,fb0 (slot ss = tile g+1) | stage B1(g+1)
    VM2(); BAR(); CFENCE();
    RD_A(fa0, ss, 0); RD_B(fb0, ss, 0);
    STG_B1(ss, st);
    __builtin_amdgcn_s_setprio(1); MM(fa1, fb1, 1, 1); __builtin_amdgcn_s_setprio(0);
  }

  const int fr = l & 15, fro = (l >> 4) * 4;
  if constexpr (MODE == 0) {
    const float* bias = (matsel == 0) ? b0 : (matsel == 1) ? b1 : b2;
    u16* ob = (matsel == 0) ? Oq : (matsel == 1) ? Ok : Ov;
    const int cb = (tn % 3) * 256 + wn * 64;
    const size_t rb = (size_t)tmz * 256 + wm * 128;
    #pragma unroll
    for (int MI = 0; MI < 8; ++MI)
      #pragma unroll
      for (int NI = 0; NI < 4; ++NI) {
        const int col = cb + NI * 16 + fr;
        const float bvv = bias[col];
        #pragma unroll
        for (int r = 0; r < 4; ++r)
          ob[(rb + MI * 16 + fro + r) * DD + col] = f2bf(acc[MI][NI][r] + bvv);
      }
  } else if constexpr (MODE == 1) {
    const int cb = tn * 256 + wn * 64;
    const size_t rb = (size_t)tmz * 256 + wm * 128;
    #pragma unroll
    for (int MI = 0; MI < 8; ++MI)
      #pragma unroll
      for (int NI = 0; NI < 4; ++NI) {
        const int col = cb + NI * 16 + fr;
        const float bvv = b0[col];
        #pragma unroll
        for (int r = 0; r < 4; ++r)
          FO[(rb + MI * 16 + fro + r) * DD + col] = acc[MI][NI][r] + bvv;
      }
  } else {
    const int cb = tn * 256 + wn * 64;
    const size_t rb = (size_t)tmz * NN + wm * 128;
    #pragma unroll
    for (int MI = 0; MI < 8; ++MI)
      #pragma unroll
      for (int NI = 0; NI < 4; ++NI) {
        const int col = cb + NI * 16 + fr;
        #pragma unroll
        for (int r = 0; r < 4; ++r)
          Oq[(rb + MI * 16 + fro + r) * DD + col] = f2bf(acc[MI][NI][r]);
      }
  }
}

// ---------------- 128x128 B^T GEMM for S = Q K^T * scale (round-4 proven) ----------------

__global__ __launch_bounds__(256)
void gemm_s(const u16* __restrict__ A, const u16* __restrict__ Bm,
            float* __restrict__ F0)
{
  const int tid = threadIdx.x;
  const int l  = tid & 63;
  const int w  = tid >> 6;
  const int wm = w >> 1, wn = w & 1;
  const int tm = blockIdx.x, tn = blockIdx.y, z = blockIdx.z;

  __shared__ u16 lsA[128 * 32];
  __shared__ u16 lsB[128 * 32];

  const u16* Abase = A + ((size_t)z * NN + tm * 128) * DD;

  f32x4 acc[4][4];
  #pragma unroll
  for (int i = 0; i < 4; i++)
    #pragma unroll
    for (int j = 0; j < 4; j++) acc[i][j] = (f32x4){0.f, 0.f, 0.f, 0.f};

  const int srow = l >> 2;
  const int scol = (l & 3) * 8;

  for (int kt = 0; kt < 24; ++kt) {
    const int kpos = kt * 32 + scol;
    #pragma unroll
    for (int q = 0; q < 2; ++q) {
      const int r = q * 64 + w * 16 + srow;
      gload_lds16(Abase + (size_t)r * DD + kpos, &lsA[q * 2048 + w * 512]);
    }
    #pragma unroll
    for (int q = 0; q < 2; ++q) {
      const int r = q * 64 + w * 16 + srow;
      const int t = tn * 128 + r;
      const int rr = (t < NN) ? (z * NN + t)
                   : ((t < TT) ? (BB * NN + t - NN) : BB * NN);
      gload_lds16(Bm + (size_t)rr * DD + kpos, &lsB[q * 2048 + w * 512]);
    }
    __syncthreads();

    const int fr = l & 15, fk = (l >> 4) * 8;
    short8 fa[4], fb[4];
    #pragma unroll
    for (int mi = 0; mi < 4; mi++)
      fa[mi] = *(const short8*)&lsA[(wm * 64 + mi * 16 + fr) * 32 + fk];
    #pragma unroll
    for (int ni = 0; ni < 4; ni++)
      fb[ni] = *(const short8*)&lsB[(wn * 64 + ni * 16 + fr) * 32 + fk];
    #pragma unroll
    for (int mi = 0; mi < 4; mi++)
      #pragma unroll
      for (int ni = 0; ni < 4; ni++)
        acc[mi][ni] = __builtin_amdgcn_mfma_f32_16x16x32_bf16(fa[mi], fb[ni], acc[mi][ni], 0, 0, 0);
    __syncthreads();
  }

  const int fr  = l & 15;
  const int fro = (l >> 4) * 4;
  const float scl = 0.03608439182435161f;  // 768^-0.5
  float* Sb = F0 + (size_t)z * NN * SP;
  const int cb = tn * 128 + wn * 64;
  const int rb = tm * 128 + wm * 64;
  #pragma unroll
  for (int mi = 0; mi < 4; mi++)
    #pragma unroll
    for (int ni = 0; ni < 4; ni++)
      #pragma unroll
      for (int r = 0; r < 4; r++)
        Sb[(size_t)(rb + mi * 16 + fro + r) * SP + cb + ni * 16 + fr] = acc[mi][ni][r] * scl;
}

// ---------------- softmax: one wave per row of S[32768][384], cols 0..263 valid ----------------

__global__ __launch_bounds__(256)
void softmax_k(const float* __restrict__ S, u16* __restrict__ P) {
  const int l = threadIdx.x & 63;
  const int row = blockIdx.x * 4 + (threadIdx.x >> 6);
  const float* s = S + (size_t)row * SP;
  float v0 = s[l], v1 = s[64 + l], v2 = s[128 + l], v3 = s[192 + l];
  float v4 = (l < 8) ? s[256 + l] : -__builtin_inff();
  float m = fmaxf(fmaxf(fmaxf(v0, v1), fmaxf(v2, v3)), v4);
  #pragma unroll
  for (int off = 32; off; off >>= 1) m = fmaxf(m, __shfl_xor(m, off));
  float e0 = __expf(v0 - m), e1 = __expf(v1 - m), e2 = __expf(v2 - m), e3 = __expf(v3 - m);
  float e4 = (l < 8) ? __expf(v4 - m) : 0.f;
  float sum = e0 + e1 + e2 + e3 + e4;
  #pragma unroll
  for (int off = 32; off; off >>= 1) sum += __shfl_xor(sum, off);
  const float inv = 1.f / sum;
  u16* p = P + (size_t)row * TP;
  p[l] = f2bf(e0 * inv); p[64 + l] = f2bf(e1 * inv);
  p[128 + l] = f2bf(e2 * inv); p[192 + l] = f2bf(e3 * inv);
  if (l < 8) p[256 + l] = f2bf(e4 * inv);
  else       p[256 + l] = 0;            // zero pad cols 264..319
}

// ---------------- V transpose: Vt[b][d][t] (t padded to 320 with zeros) ----------------

__global__ __launch_bounds__(256)
void transpose_v(const u16* __restrict__ V, u16* __restrict__ Vt) {
  __shared__ u16 ls[64 * 66];
  const int b = blockIdx.z;
  const int d0 = blockIdx.x * 64;
  const int t0 = blockIdx.y * 64;
  const int tid = threadIdx.x;
  #pragma unroll
  for (int q = 0; q < 2; ++q) {
    const int idx = q * 256 + tid;
    const int tr = idx >> 3;
    const int dg = (idx & 7) * 8;
    const int t = t0 + tr;
    short8 v = (short8)(short)0;
    if (t < NN)       v = *(const short8*)(V + ((size_t)b * NN + t) * DD + d0 + dg);
    else if (t < TT)  v = *(const short8*)(V + (size_t)(BB * NN + t - NN) * DD + d0 + dg);
    #pragma unroll
    for (int e = 0; e < 8; ++e) ls[tr * 66 + dg + e] = (u16)v[e];
  }
  __syncthreads();
  #pragma unroll
  for (int q = 0; q < 2; ++q) {
    const int idx = q * 256 + tid;
    const int dr = idx >> 3;
    const int tg = (idx & 7) * 8;
    short8 v;
    #pragma unroll
    for (int e = 0; e < 8; ++e) v[e] = (short)ls[(tg + e) * 66 + dr];
    *(short8*)(Vt + ((size_t)b * DD + d0 + dr) * TP + t0 + tg) = v;
  }
}

// ---------------- launch ----------------
// Order: conv_x, conv_w -> G1 -> G2a(S) -> softmax -> transpose_v -> G2c(PV) -> G3.
// d_out (100.66 MB): Ab [0,50.72M) live conv_x->G1; S [0,50.33M) live G2a->softmax;
//   P [50.72M,71.70M) live softmax->G2c; W^T(q,k,v) [97.12M,100.66M) live conv_w->G1.
//   All dead before G3 overwrites d_out.  (round-4 proven plan)
// ws (high-water 153.35 MB, proven): Qb@0, Kb@50.72M (live G1->G2a);
//   Vb@101.45M (live G1->transpose_v); Vt@0 (62.91M over dead Qb+Kb-head,
//   live transpose_v->G2c); O@62.91M (50.33M over dead Kb-tail+Vb-head,
//   live G2c->G3); Wot@152.17M (live conv_w->G3).

extern "C" void kernel_launch(void* const* d_in, const int* in_sizes, int n_in,
                              void* d_out, int out_size, void* d_ws, size_t ws_size,
                              hipStream_t stream) {
  const float* x   = (const float*)d_in[0];
  const float* mem = (const float*)d_in[1];
  const float* Wq  = (const float*)d_in[2];
  const float* bq  = (const float*)d_in[3];
  const float* Wk  = (const float*)d_in[4];
  const float* bk  = (const float*)d_in[5];
  const float* Wv  = (const float*)d_in[6];
  const float* bv  = (const float*)d_in[7];
  const float* Wo  = (const float*)d_in[8];
  const float* bo  = (const float*)d_in[9];
  float* out = (float*)d_out;
  (void)ws_size; (void)in_sizes; (void)n_in; (void)out_size;

  const size_t QKV_B = (size_t)AROWS2 * DD * 2;        // 50,724,864
  char* wsb = (char*)d_ws;
  u16* Qb  = (u16*)(wsb);
  u16* Kb  = (u16*)(wsb + QKV_B);
  u16* Vb  = (u16*)(wsb + 2 * QKV_B);
  u16* Vt  = (u16*)(wsb);                              // over dead Qb+Kb head
  u16* O   = (u16*)(wsb + (size_t)BB * DD * TP * 2);   // @62,914,560
  u16* Wot = (u16*)(wsb + 3 * QKV_B);                  // @152,174,592

  u16*   Ab  = (u16*)d_out;                            // live conv_x -> G1
  float* S   = (float*)d_out;                          // live G2a -> softmax
  u16*   P   = (u16*)((char*)d_out + QKV_B);           // live softmax -> G2c
  u16*   Wqt = (u16*)((char*)d_out + 97124352);        // live conv_w -> G1
  u16*   Wkt = Wqt + (size_t)DD * DD;
  u16*   Wvt = Wkt + (size_t)DD * DD;

  conv_x<<<2048, 256, 0, stream>>>(x, mem, Ab);
  conv_w<<<1024, 256, 0, stream>>>(Wq, Wk, Wv, Wo, Wqt, Wkt, Wvt, Wot);

  // G1: QKV projection  [33024 x 2304] = Ab @ [Wqt|Wkt|Wvt]^T  (+bias, -> bf16)
  gemm256<0><<<dim3(9, 129), 512, 131072, stream>>>(
      Ab, Wqt, Wkt, Wvt, bq, bk, bv, Qb, Kb, Vb, nullptr, 12);

  // G2a: S = Q @ K^T * scale  (per batch, K-rows remapped over [x;memory])
  gemm_s<<<dim3(2, 3, BB), 256, 0, stream>>>(Qb, Kb, S);

  // softmax rows -> P (bf16, zero-padded to 320 cols)
  softmax_k<<<8192, 256, 0, stream>>>(S, P);

  // Vt[b][d][t]  (writes over dead Qb/Kb region)
  transpose_v<<<dim3(12, 5, BB), 256, 0, stream>>>(Vb, Vt);

  // G2c: O = P @ Vt^T per batch (pipelined 256-tile, K=320)
  gemm256<2><<<dim3(3, 128), 512, 131072, stream>>>(
      P, Vt, nullptr, nullptr, nullptr, nullptr, nullptr,
      O, nullptr, nullptr, nullptr, 5);

  // G3: out = O @ Wot^T + bo  (fp32)
  gemm256<1><<<dim3(3, 128), 512, 131072, stream>>>(
      O, Wot, nullptr, nullptr, bo, nullptr, nullptr,
      nullptr, nullptr, nullptr, out, 12);
}